// Round 10
// baseline (145.723 us; speedup 1.0000x reference)
//
#include <hip/hip_runtime.h>
#include <math.h>

#define IN_DIM 5
constexpr int B = 8192;
constexpr int N = 100;
constexpr float DT     = 0.01f;
constexpr float MU_DT  = 0.001f;
constexpr float NU     = 0.2f;
constexpr float SIGMA  = 0.3f;
constexpr float BN_EPS = 1e-5f;
constexpr float FLOORV = 1e-4f;

typedef __attribute__((ext_vector_type(8))) short short8;
typedef __attribute__((ext_vector_type(4))) float f32x4;

// truncation-based bf16 split: h = hi + lo with |err| ~ 2^-16 |h|
__device__ __forceinline__ void bf16_split(float h, short& hi, short& lo) {
    unsigned int ub = __builtin_bit_cast(unsigned int, h);
    hi = (short)(ub >> 16);
    float hif = __builtin_bit_cast(float, ub & 0xffff0000u);
    float l = h - hif;
    lo = (short)(__builtin_bit_cast(unsigned int, l) >> 16);
}

// sum over each aligned 16-lane group via DPP (VALU only, no DS pipe)
__device__ __forceinline__ float red16(float v) {
#if __has_builtin(__builtin_amdgcn_update_dpp)
    int x;
    x = __builtin_amdgcn_update_dpp(0, __builtin_bit_cast(int, v), 0xB1, 0xF, 0xF, false);
    v += __builtin_bit_cast(float, x);
    x = __builtin_amdgcn_update_dpp(0, __builtin_bit_cast(int, v), 0x4E, 0xF, 0xF, false);
    v += __builtin_bit_cast(float, x);
    x = __builtin_amdgcn_update_dpp(0, __builtin_bit_cast(int, v), 0x141, 0xF, 0xF, false);
    v += __builtin_bit_cast(float, x);
    x = __builtin_amdgcn_update_dpp(0, __builtin_bit_cast(int, v), 0x140, 0xF, 0xF, false);
    v += __builtin_bit_cast(float, x);
    return v;
#else
    v += __shfl_xor(v, 1);
    v += __shfl_xor(v, 2);
    v += __shfl_xor(v, 4);
    v += __shfl_xor(v, 8);
    return v;
#endif
}

// ---------------------------------------------------------------------------
// Kernel 1: batch-norm stats (unchanged).
// ws[0..4]=alpha, ws[5..9]=beta', ws[10..14]=alphac, ws[15..19]=betac'
// ---------------------------------------------------------------------------
__global__ __launch_bounds__(1024) void bn_stats_kernel(
    const float* __restrict__ tv,
    const float* __restrict__ g1, const float* __restrict__ be1,
    const float* __restrict__ g2, const float* __restrict__ be2,
    float* __restrict__ ws)
{
    const int t = threadIdx.x;
    float s[IN_DIM] = {0.f, 0.f, 0.f, 0.f, 0.f};
    float q[IN_DIM] = {0.f, 0.f, 0.f, 0.f, 0.f};
    for (int r = t; r < B; r += 1024) {
        const float* row = tv + r * IN_DIM;
#pragma unroll
        for (int k = 0; k < IN_DIM; ++k) {
            const float v = row[k];
            s[k] += v;
            q[k] += v * v;
        }
    }
#pragma unroll
    for (int k = 0; k < IN_DIM; ++k) {
#pragma unroll
        for (int off = 32; off >= 1; off >>= 1) {
            s[k] += __shfl_xor(s[k], off);
            q[k] += __shfl_xor(q[k], off);
        }
    }
    __shared__ float red[16][2 * IN_DIM];
    const int w = t >> 6, lane = t & 63;
    if (lane == 0) {
#pragma unroll
        for (int k = 0; k < IN_DIM; ++k) {
            red[w][k] = s[k];
            red[w][IN_DIM + k] = q[k];
        }
    }
    __syncthreads();
    if (t == 0) {
#pragma unroll
        for (int k = 0; k < IN_DIM; ++k) {
            float S = 0.f, Q = 0.f;
            for (int u = 0; u < 16; ++u) { S += red[u][k]; Q += red[u][IN_DIM + k]; }
            const float mean = S / (float)B;
            const float var  = Q / (float)B - mean * mean;
            const float inv  = 1.0f / sqrtf(var + BN_EPS);
            const float a1 = inv * g1[k];
            const float a2 = inv * g2[k];
            ws[k]          = a1;
            ws[IN_DIM + k] = be1[k] - mean * a1;
            ws[10 + k]     = a2;
            ws[15 + k]     = be2[k] - mean * a2;
        }
    }
}

// ---------------------------------------------------------------------------
// Kernel 2: simulation. Block = 512 thr = 8 waves over the SAME 16 samples.
// wave (mlp = w&1, q = (w>>1)&1, h = w>>2):
//   L1: units 32q..32q+31 (8/lane, dup across h only); h==0 waves publish
//       the (mlp,q) A-frags to FX; barrier A; all read the other-q frag.
//   L2: nt in {2h,2h+1}, BOTH kt (relu needs the full-k sum): 12 MFMAs as
//       two independent 3-deep chains per ntl (own-q regs / exchanged frags).
//   L3: partial head for its 2 nt -> ex[i&1] comp (2h+mlp) (q==0 publishes);
//       barrier B; SDE redundant in all 8 waves.
// 512 blocks x 8 waves = 4096 waves = 4 waves/SIMD (vs 2 before) -- doubles
// the stall-hiding TLP at ~equal per-SIMD issue. launch_bounds(512,4) caps
// VGPR at 128 so 4/SIMD is achievable. Zero global ops inside the loop.
// ---------------------------------------------------------------------------
__global__ __launch_bounds__(512, 4) void sim_kernel(
    const float* __restrict__ bm, const float* __restrict__ cn,
    const float* __restrict__ typeVec,
    const float* __restrict__ mx, const float* __restrict__ mc,
    const float* __restrict__ initial,
    const float* __restrict__ w1, const float* __restrict__ b1,
    const float* __restrict__ w2, const float* __restrict__ b2,
    const float* __restrict__ w3, const float* __restrict__ b3,
    const float* __restrict__ wc1, const float* __restrict__ bc1,
    const float* __restrict__ wc2, const float* __restrict__ bc2,
    const float* __restrict__ wc3, const float* __restrict__ bc3,
    const float* __restrict__ ws, float* __restrict__ out)
{
    const int tid = threadIdx.x;
    const int wid = tid >> 6;        // 0..7
    const int l   = tid & 63;
    const int s   = l & 15;          // sample (A-row) / unit-col index
    const int g   = l >> 4;          // k-octet / D-row group
    const int mlp = wid & 1;         // 0 = pi-MLP, 1 = c-MLP
    const int q   = (wid >> 1) & 1;  // k-half owned in layer-1
    const int h   = wid >> 2;        // nt half: columns {2h, 2h+1}
    const int b0  = blockIdx.x * 16;

    __shared__ float4 SI[N][16];       // [step][sample] = {bm, dcn, mx, mc}
    __shared__ float  traj[N + 1][16];
    __shared__ float4 ex[2][16];       // [buf][sample] comp (2h+mlp)
    __shared__ short8 FX[2][2][2][64]; // [mlp][q][hi/lo][lane] A-frag exchange

    // ---- stage per-step inputs, coalesced ----
#pragma unroll
    for (int k = 0; k < 4; ++k) {
        const int f  = tid + 512 * k;       // < 2048
        const int ss = f >> 7;
        const int ii = f & 127;
        if (ii < N) {
            const size_t r = (size_t)(b0 + ss);
            const float vb = bm[r * N + ii];
            const float c0 = cn[r * (N + 1) + ii];
            const float c1 = cn[r * (N + 1) + ii + 1];
            const float vx = mx[r * (N + 1) + ii];
            const float vc = mc[r * N + ii];
            SI[ii][ss] = make_float4(vb, c1 - c0, vx, vc);
        }
    }

    // ---- this wave's MLP parameter set ----
    const float* W1 = mlp ? wc1 : w1;
    const float* B1 = mlp ? bc1 : b1;
    const float* W2 = mlp ? wc2 : w2;
    const float* B2 = mlp ? bc2 : b2;
    const float* W3 = mlp ? wc3 : w3;
    const float* B3 = mlp ? bc3 : b3;
    const float* alpha = ws + (mlp ? 10 : 0);
    const float* beta  = ws + (mlp ? 15 : 5);

    // ---- B-fragments of W2 (hi/lo): O pairs own-q A-frags, X the other ----
    short8 BhO[2], BlO[2], BhX[2], BlX[2];
#pragma unroll
    for (int ntl = 0; ntl < 2; ++ntl) {
        const int nt = 2 * h + ntl;
        short8 fhO, flO, fhX, flX;
#pragma unroll
        for (int e = 0; e < 8; ++e) {
            short hi, lo;
            bf16_split(W2[(32 * q + 8 * g + e) * 64 + 16 * nt + s], hi, lo);
            fhO[e] = hi; flO[e] = lo;
            bf16_split(W2[(32 * (1 - q) + 8 * g + e) * 64 + 16 * nt + s], hi, lo);
            fhX[e] = hi; flX[e] = lo;
        }
        BhO[ntl] = fhO; BlO[ntl] = flO;
        BhX[ntl] = fhX; BlX[ntl] = flX;
    }

    // ---- bn affine for this lane's sample; layer-1 consts (8 own units) ----
    float bnv[IN_DIM];
    {
        const float* tvp = typeVec + (size_t)(b0 + s) * IN_DIM;
#pragma unroll
        for (int k = 0; k < IN_DIM; ++k)
            bnv[k] = fmaf(tvp[k], alpha[k], beta[k]);
    }
    float bs[8], wt[8], wx[8], wm[8], wcr[8];
#pragma unroll
    for (int j = 0; j < 8; ++j) {
        const int u = 32 * q + 8 * g + j;
        wt[j]  = W1[5 * 64 + u];
        wx[j]  = W1[6 * 64 + u];
        wm[j]  = W1[7 * 64 + u];
        wcr[j] = W1[8 * 64 + u];
        float a = B1[u];
#pragma unroll
        for (int k = 0; k < IN_DIM; ++k) a = fmaf(bnv[k], W1[k * 64 + u], a);
        bs[j] = a;
    }
    float b2v[2], w3v[2];
#pragma unroll
    for (int ntl = 0; ntl < 2; ++ntl) {
        const int nt = 2 * h + ntl;
        b2v[ntl] = B2[16 * nt + s];
        w3v[ntl] = W3[16 * nt + s];
    }
    const float b3s = B3[0];
    const float x0  = initial[0];

    float x = x0;
    if (tid < 16) traj[0][tid] = x0;
    __syncthreads();

    float4 in_cur = SI[0][s];

    for (int i = 0; i < N; ++i) {
        const float t = (float)i * DT;
        const float4 in = in_cur;              // {bm, dcn, mx, mc}
        if (i + 1 < N) in_cur = SI[i + 1][s];  // prefetch next step

        // ---- layer-1: 8 own k-units, relu, hi/lo split ----
        short8 oh, ol;
#pragma unroll
        for (int j = 0; j < 8; ++j) {
            float hv = bs[j];
            hv = fmaf(t,    wt[j],  hv);
            hv = fmaf(x,    wx[j],  hv);
            hv = fmaf(in.z, wm[j],  hv);
            hv = fmaf(in.w, wcr[j], hv);
            hv = fmaxf(hv, 0.0f);
            short hi, lo;
            bf16_split(hv, hi, lo);
            oh[j] = hi; ol[j] = lo;
        }
        // h==0 waves publish the (mlp,q) A-frags (h==1 computed identical)
        if (h == 0) {
            FX[mlp][q][0][l] = oh;
            FX[mlp][q][1][l] = ol;
        }
        __syncthreads();                       // barrier A
        const short8 xh = FX[mlp][1 - q][0][l];
        const short8 xl = FX[mlp][1 - q][1][l];

        // ---- layer-2 MFMA: both kt for this wave's 2 nt (12 MFMAs) ----
        f32x4 acc0[2], acc1[2];
#pragma unroll
        for (int ntl = 0; ntl < 2; ++ntl) {
            acc0[ntl] = (f32x4){b2v[ntl], b2v[ntl], b2v[ntl], b2v[ntl]};
            acc1[ntl] = (f32x4){0.f, 0.f, 0.f, 0.f};
        }
#pragma unroll
        for (int ntl = 0; ntl < 2; ++ntl) {
            acc0[ntl] = __builtin_amdgcn_mfma_f32_16x16x32_bf16(oh, BhO[ntl], acc0[ntl], 0, 0, 0);
            acc0[ntl] = __builtin_amdgcn_mfma_f32_16x16x32_bf16(ol, BhO[ntl], acc0[ntl], 0, 0, 0);
            acc0[ntl] = __builtin_amdgcn_mfma_f32_16x16x32_bf16(oh, BlO[ntl], acc0[ntl], 0, 0, 0);
            acc1[ntl] = __builtin_amdgcn_mfma_f32_16x16x32_bf16(xh, BhX[ntl], acc1[ntl], 0, 0, 0);
            acc1[ntl] = __builtin_amdgcn_mfma_f32_16x16x32_bf16(xl, BhX[ntl], acc1[ntl], 0, 0, 0);
            acc1[ntl] = __builtin_amdgcn_mfma_f32_16x16x32_bf16(xh, BlX[ntl], acc1[ntl], 0, 0, 0);
        }

        // ---- layer-3 partial: relu * w3 (full-k sum first), DPP-reduce ----
        f32x4 rv = (f32x4){0.f, 0.f, 0.f, 0.f};
        const f32x4 z4 = (f32x4){0.f, 0.f, 0.f, 0.f};
#pragma unroll
        for (int ntl = 0; ntl < 2; ++ntl) {
            const f32x4 fs  = acc0[ntl] + acc1[ntl];
            const f32x4 rel = __builtin_elementwise_max(fs, z4);
            const f32x4 wsp = (f32x4){w3v[ntl], w3v[ntl], w3v[ntl], w3v[ntl]};
            rv = __builtin_elementwise_fma(rel, wsp, rv);
        }
        const float r0 = red16(rv[0]);
        const float r1 = red16(rv[1]);
        const float r2 = red16(rv[2]);
        const float r3 = red16(rv[3]);

        // q==0 waves publish: lanes r4<4 of group g own sample 4g+r4
        const int r4 = l & 15;
        float wv = r0;
        wv = (r4 == 1) ? r1 : wv;
        wv = (r4 == 2) ? r2 : wv;
        wv = (r4 == 3) ? r3 : wv;
        if (h == 0) wv += b3s;       // bias counted once per MLP
        if (q == 0 && r4 < 4) ((float*)&ex[i & 1][4 * g + r4])[2 * h + mlp] = wv;
        __syncthreads();             // barrier B

        // ---- merge partials, SDE update (redundant in all 8 waves) ----
        const float4 pv = ex[i & 1][s];   // {pi_h0, cl_h0, pi_h1, cl_h1}
        const float pi_v = pv.x + pv.z;
        const float c_v  = __expf(pv.y + pv.w);
        const float drift = MU_DT + fmaf(NU, in.x, SIGMA * in.y);
        float xn = x + pi_v * x * drift - c_v * x * DT;
        xn = fmaxf(xn - FLOORV, 0.0f) + FLOORV;
        x = xn;

        if (tid < 16) traj[i + 1][tid] = x;
    }
    __syncthreads();

    // ---- epilogue: coalesced output write {t, x} ----
    const int TOT = 16 * (N + 1) * 2;            // 3232
#pragma unroll
    for (int k = 0; k < 7; ++k) {
        const int e = tid + 512 * k;
        if (e < TOT) {
            const int sample = e / (2 * (N + 1));
            const int r      = e - sample * (2 * (N + 1));
            const int i      = r >> 1;
            const float v    = (r & 1) ? traj[i][sample] : (float)i * DT;
            out[(size_t)b0 * (2 * (N + 1)) + e] = v;
        }
    }
}

extern "C" void kernel_launch(void* const* d_in, const int* in_sizes, int n_in,
                              void* d_out, int out_size, void* d_ws, size_t ws_size,
                              hipStream_t stream) {
    const float* bm        = (const float*)d_in[0];
    const float* cn        = (const float*)d_in[1];
    const float* typeVec   = (const float*)d_in[2];
    const float* mx        = (const float*)d_in[3];
    const float* mc        = (const float*)d_in[4];
    const float* initial   = (const float*)d_in[5];
    const float* bn_gamma  = (const float*)d_in[6];
    const float* bn_beta   = (const float*)d_in[7];
    const float* bnc_gamma = (const float*)d_in[8];
    const float* bnc_beta  = (const float*)d_in[9];
    const float* w1  = (const float*)d_in[10];
    const float* b1  = (const float*)d_in[11];
    const float* w2  = (const float*)d_in[12];
    const float* b2  = (const float*)d_in[13];
    const float* w3  = (const float*)d_in[14];
    const float* b3  = (const float*)d_in[15];
    const float* wc1 = (const float*)d_in[16];
    const float* bc1 = (const float*)d_in[17];
    const float* wc2 = (const float*)d_in[18];
    const float* bc2 = (const float*)d_in[19];
    const float* wc3 = (const float*)d_in[20];
    const float* bc3 = (const float*)d_in[21];
    float* wsp = (float*)d_ws;
    float* out = (float*)d_out;

    bn_stats_kernel<<<1, 1024, 0, stream>>>(typeVec, bn_gamma, bn_beta,
                                            bnc_gamma, bnc_beta, wsp);
    sim_kernel<<<512, 512, 0, stream>>>(bm, cn, typeVec, mx, mc, initial,
                                        w1, b1, w2, b2, w3, b3,
                                        wc1, bc1, wc2, bc2, wc3, bc3,
                                        wsp, out);
}

// Round 11
// 138.463 us; speedup vs baseline: 1.0524x; 1.0524x over previous
//
#include <hip/hip_runtime.h>
#include <math.h>

#define IN_DIM 5
constexpr int B = 8192;
constexpr int N = 100;
constexpr float DT     = 0.01f;
constexpr float MU_DT  = 0.001f;
constexpr float NU     = 0.2f;
constexpr float SIGMA  = 0.3f;
constexpr float BN_EPS = 1e-5f;
constexpr float FLOORV = 1e-4f;

typedef __attribute__((ext_vector_type(8))) short short8;
typedef __attribute__((ext_vector_type(4))) float f32x4;

// truncation-based bf16 split: h = hi + lo with |err| ~ 2^-16 |h|
__device__ __forceinline__ void bf16_split(float h, short& hi, short& lo) {
    unsigned int ub = __builtin_bit_cast(unsigned int, h);
    hi = (short)(ub >> 16);
    float hif = __builtin_bit_cast(float, ub & 0xffff0000u);
    float l = h - hif;
    lo = (short)(__builtin_bit_cast(unsigned int, l) >> 16);
}

// sum over each aligned 16-lane group via DPP (VALU only, no DS pipe)
__device__ __forceinline__ float red16(float v) {
#if __has_builtin(__builtin_amdgcn_update_dpp)
    int x;
    x = __builtin_amdgcn_update_dpp(0, __builtin_bit_cast(int, v), 0xB1, 0xF, 0xF, false);
    v += __builtin_bit_cast(float, x);
    x = __builtin_amdgcn_update_dpp(0, __builtin_bit_cast(int, v), 0x4E, 0xF, 0xF, false);
    v += __builtin_bit_cast(float, x);
    x = __builtin_amdgcn_update_dpp(0, __builtin_bit_cast(int, v), 0x141, 0xF, 0xF, false);
    v += __builtin_bit_cast(float, x);
    x = __builtin_amdgcn_update_dpp(0, __builtin_bit_cast(int, v), 0x140, 0xF, 0xF, false);
    v += __builtin_bit_cast(float, x);
    return v;
#else
    v += __shfl_xor(v, 1);
    v += __shfl_xor(v, 2);
    v += __shfl_xor(v, 4);
    v += __shfl_xor(v, 8);
    return v;
#endif
}

// ---------------------------------------------------------------------------
// Kernel 1: batch-norm stats (unchanged).
// ws[0..4]=alpha, ws[5..9]=beta', ws[10..14]=alphac, ws[15..19]=betac'
// ---------------------------------------------------------------------------
__global__ __launch_bounds__(1024) void bn_stats_kernel(
    const float* __restrict__ tv,
    const float* __restrict__ g1, const float* __restrict__ be1,
    const float* __restrict__ g2, const float* __restrict__ be2,
    float* __restrict__ ws)
{
    const int t = threadIdx.x;
    float s[IN_DIM] = {0.f, 0.f, 0.f, 0.f, 0.f};
    float q[IN_DIM] = {0.f, 0.f, 0.f, 0.f, 0.f};
    for (int r = t; r < B; r += 1024) {
        const float* row = tv + r * IN_DIM;
#pragma unroll
        for (int k = 0; k < IN_DIM; ++k) {
            const float v = row[k];
            s[k] += v;
            q[k] += v * v;
        }
    }
#pragma unroll
    for (int k = 0; k < IN_DIM; ++k) {
#pragma unroll
        for (int off = 32; off >= 1; off >>= 1) {
            s[k] += __shfl_xor(s[k], off);
            q[k] += __shfl_xor(q[k], off);
        }
    }
    __shared__ float red[16][2 * IN_DIM];
    const int w = t >> 6, lane = t & 63;
    if (lane == 0) {
#pragma unroll
        for (int k = 0; k < IN_DIM; ++k) {
            red[w][k] = s[k];
            red[w][IN_DIM + k] = q[k];
        }
    }
    __syncthreads();
    if (t == 0) {
#pragma unroll
        for (int k = 0; k < IN_DIM; ++k) {
            float S = 0.f, Q = 0.f;
            for (int u = 0; u < 16; ++u) { S += red[u][k]; Q += red[u][IN_DIM + k]; }
            const float mean = S / (float)B;
            const float var  = Q / (float)B - mean * mean;
            const float inv  = 1.0f / sqrtf(var + BN_EPS);
            const float a1 = inv * g1[k];
            const float a2 = inv * g2[k];
            ws[k]          = a1;
            ws[IN_DIM + k] = be1[k] - mean * a1;
            ws[10 + k]     = a2;
            ws[15 + k]     = be2[k] - mean * a2;
        }
    }
}

// ---------------------------------------------------------------------------
// Kernel 2: simulation. Block = 256 thr = 4 waves (R5's proven mlp x q roles)
// but each wave now carries TWO independent 16-sample groups (A: samples
// b0..b0+15, B: b0+16..b0+31) -> 2x ILP per wave. Stalls of one group's
// FX/ex LDS round-trips, weight reloads and MFMA chains hide under the other
// group's instruction stream. Grid = 256 blocks (1/CU), 1024 waves.
// Inputs via per-lane register prefetch (1 step ahead; no SI staging --
// R3 vs R4 showed staging was neutral, and dropping it frees LDS for FX x2).
// Weights (B-frags, layer-1 consts) shared across the two groups.
// ---------------------------------------------------------------------------
__global__ __launch_bounds__(256, 1) void sim_kernel(
    const float* __restrict__ bm, const float* __restrict__ cn,
    const float* __restrict__ typeVec,
    const float* __restrict__ mx, const float* __restrict__ mc,
    const float* __restrict__ initial,
    const float* __restrict__ w1, const float* __restrict__ b1,
    const float* __restrict__ w2, const float* __restrict__ b2,
    const float* __restrict__ w3, const float* __restrict__ b3,
    const float* __restrict__ wc1, const float* __restrict__ bc1,
    const float* __restrict__ wc2, const float* __restrict__ bc2,
    const float* __restrict__ wc3, const float* __restrict__ bc3,
    const float* __restrict__ ws, float* __restrict__ out)
{
    const int tid = threadIdx.x;
    const int wid = tid >> 6;        // 0..3
    const int l   = tid & 63;
    const int s   = l & 15;          // sample-in-group / unit-col index
    const int g   = l >> 4;          // k-octet / D-row group
    const int mlp = wid & 1;         // 0 = pi-MLP, 1 = c-MLP
    const int q   = wid >> 1;        // k-half (layer-1) and kt role
    const int b0  = blockIdx.x * 32; // 32 samples: group A = +s, group B = +16+s

    __shared__ float  traj[N + 1][32];
    __shared__ float4 ex[32];             // [sample] = partials {w0,w1,w2,w3}
    __shared__ short8 FX[2][2][2][2][64]; // [grp][mlp][q][hi/lo][lane]

    // ---- this wave's MLP parameter set ----
    const float* W1 = mlp ? wc1 : w1;
    const float* B1 = mlp ? bc1 : b1;
    const float* W2 = mlp ? wc2 : w2;
    const float* B2 = mlp ? bc2 : b2;
    const float* W3 = mlp ? wc3 : w3;
    const float* B3 = mlp ? bc3 : b3;
    const float* alpha = ws + (mlp ? 10 : 0);
    const float* beta  = ws + (mlp ? 15 : 5);

    // ---- B-fragments of W2 (hi/lo), per-role: O = kt=q, X = kt=1-q ----
    short8 BhO[2], BlO[2], BhX[2], BlX[2];
#pragma unroll
    for (int ntl = 0; ntl < 2; ++ntl) {
        const int nt = 2 * q + ntl;
        short8 fhO, flO, fhX, flX;
#pragma unroll
        for (int e = 0; e < 8; ++e) {
            short hi, lo;
            bf16_split(W2[(32 * q + 8 * g + e) * 64 + 16 * nt + s], hi, lo);
            fhO[e] = hi; flO[e] = lo;
            bf16_split(W2[(32 * (1 - q) + 8 * g + e) * 64 + 16 * nt + s], hi, lo);
            fhX[e] = hi; flX[e] = lo;
        }
        BhO[ntl] = fhO; BlO[ntl] = flO;
        BhX[ntl] = fhX; BlX[ntl] = flX;
    }

    // ---- bn affine for BOTH samples; layer-1 consts (weights shared) ----
    float bnvA[IN_DIM], bnvB[IN_DIM];
    {
        const float* tvpA = typeVec + (size_t)(b0 + s) * IN_DIM;
        const float* tvpB = typeVec + (size_t)(b0 + 16 + s) * IN_DIM;
#pragma unroll
        for (int k = 0; k < IN_DIM; ++k) {
            bnvA[k] = fmaf(tvpA[k], alpha[k], beta[k]);
            bnvB[k] = fmaf(tvpB[k], alpha[k], beta[k]);
        }
    }
    float bsA[8], bsB[8], wt[8], wx[8], wm[8], wcr[8];
#pragma unroll
    for (int j = 0; j < 8; ++j) {
        const int u = 32 * q + 8 * g + j;
        wt[j]  = W1[5 * 64 + u];
        wx[j]  = W1[6 * 64 + u];
        wm[j]  = W1[7 * 64 + u];
        wcr[j] = W1[8 * 64 + u];
        float aA = B1[u], aB = B1[u];
#pragma unroll
        for (int k = 0; k < IN_DIM; ++k) {
            const float wv = W1[k * 64 + u];
            aA = fmaf(bnvA[k], wv, aA);
            aB = fmaf(bnvB[k], wv, aB);
        }
        bsA[j] = aA;
        bsB[j] = aB;
    }
    float b2v[2], w3v[2];
#pragma unroll
    for (int ntl = 0; ntl < 2; ++ntl) {
        const int nt = 2 * q + ntl;
        b2v[ntl] = B2[16 * nt + s];
        w3v[ntl] = W3[16 * nt + s];
    }
    const float b3s = B3[0];
    const float x0  = initial[0];

    // ---- per-lane input pointers (both samples) with 1-step prefetch ----
    const float* bmpA = bm + (size_t)(b0 + s) * N;
    const float* cnpA = cn + (size_t)(b0 + s) * (N + 1);
    const float* mxpA = mx + (size_t)(b0 + s) * (N + 1);
    const float* mcpA = mc + (size_t)(b0 + s) * N;
    const float* bmpB = bm + (size_t)(b0 + 16 + s) * N;
    const float* cnpB = cn + (size_t)(b0 + 16 + s) * (N + 1);
    const float* mxpB = mx + (size_t)(b0 + 16 + s) * (N + 1);
    const float* mcpB = mc + (size_t)(b0 + 16 + s) * N;
    float ccA = cnpA[0], ccB = cnpB[0];
    float pbmA = bmpA[0], pcnA = cnpA[1], pmxA = mxpA[0], pmcA = mcpA[0];
    float pbmB = bmpB[0], pcnB = cnpB[1], pmxB = mxpB[0], pmcB = mcpB[0];

    float xA = x0, xB = x0;
    if (tid < 32) traj[0][tid] = x0;
    __syncthreads();

    for (int i = 0; i < N; ++i) {
        const float t = (float)i * DT;
        const float vbmA = pbmA, vdcA = pcnA - ccA, vmxA = pmxA, vmcA = pmcA;
        const float vbmB = pbmB, vdcB = pcnB - ccB, vmxB = pmxB, vmcB = pmcB;
        ccA = pcnA; ccB = pcnB;
        if (i + 1 < N) {
            pbmA = bmpA[i + 1]; pcnA = cnpA[i + 2];
            pmxA = mxpA[i + 1]; pmcA = mcpA[i + 1];
            pbmB = bmpB[i + 1]; pcnB = cnpB[i + 2];
            pmxB = mxpB[i + 1]; pmcB = mcpB[i + 1];
        }

        // ---- layer-1: 8 own k-units per group, relu, hi/lo split ----
        short8 ohA, olA, ohB, olB;
#pragma unroll
        for (int j = 0; j < 8; ++j) {
            float hA = bsA[j];
            hA = fmaf(t,    wt[j],  hA);
            hA = fmaf(xA,   wx[j],  hA);
            hA = fmaf(vmxA, wm[j],  hA);
            hA = fmaf(vmcA, wcr[j], hA);
            hA = fmaxf(hA, 0.0f);
            float hB = bsB[j];
            hB = fmaf(t,    wt[j],  hB);
            hB = fmaf(xB,   wx[j],  hB);
            hB = fmaf(vmxB, wm[j],  hB);
            hB = fmaf(vmcB, wcr[j], hB);
            hB = fmaxf(hB, 0.0f);
            short hi, lo;
            bf16_split(hA, hi, lo); ohA[j] = hi; olA[j] = lo;
            bf16_split(hB, hi, lo); ohB[j] = hi; olB[j] = lo;
        }
        // exchange A-frags with partner wave (same mlp, other q), both groups
        FX[0][mlp][q][0][l] = ohA;
        FX[0][mlp][q][1][l] = olA;
        FX[1][mlp][q][0][l] = ohB;
        FX[1][mlp][q][1][l] = olB;
        __syncthreads();                       // barrier A
        const short8 xhA = FX[0][mlp][1 - q][0][l];
        const short8 xlA = FX[0][mlp][1 - q][1][l];
        const short8 xhB = FX[1][mlp][1 - q][0][l];
        const short8 xlB = FX[1][mlp][1 - q][1][l];

        // ---- layer-2 MFMA: two 3-deep chains per ntl, both groups ----
        f32x4 aA0[2], aA1[2], aB0[2], aB1[2];
#pragma unroll
        for (int ntl = 0; ntl < 2; ++ntl) {
            aA0[ntl] = (f32x4){b2v[ntl], b2v[ntl], b2v[ntl], b2v[ntl]};
            aA1[ntl] = (f32x4){0.f, 0.f, 0.f, 0.f};
            aB0[ntl] = aA0[ntl];
            aB1[ntl] = (f32x4){0.f, 0.f, 0.f, 0.f};
        }
#pragma unroll
        for (int ntl = 0; ntl < 2; ++ntl) {
            aA0[ntl] = __builtin_amdgcn_mfma_f32_16x16x32_bf16(ohA, BhO[ntl], aA0[ntl], 0, 0, 0);
            aA0[ntl] = __builtin_amdgcn_mfma_f32_16x16x32_bf16(olA, BhO[ntl], aA0[ntl], 0, 0, 0);
            aA0[ntl] = __builtin_amdgcn_mfma_f32_16x16x32_bf16(ohA, BlO[ntl], aA0[ntl], 0, 0, 0);
            aA1[ntl] = __builtin_amdgcn_mfma_f32_16x16x32_bf16(xhA, BhX[ntl], aA1[ntl], 0, 0, 0);
            aA1[ntl] = __builtin_amdgcn_mfma_f32_16x16x32_bf16(xlA, BhX[ntl], aA1[ntl], 0, 0, 0);
            aA1[ntl] = __builtin_amdgcn_mfma_f32_16x16x32_bf16(xhA, BlX[ntl], aA1[ntl], 0, 0, 0);
            aB0[ntl] = __builtin_amdgcn_mfma_f32_16x16x32_bf16(ohB, BhO[ntl], aB0[ntl], 0, 0, 0);
            aB0[ntl] = __builtin_amdgcn_mfma_f32_16x16x32_bf16(olB, BhO[ntl], aB0[ntl], 0, 0, 0);
            aB0[ntl] = __builtin_amdgcn_mfma_f32_16x16x32_bf16(ohB, BlO[ntl], aB0[ntl], 0, 0, 0);
            aB1[ntl] = __builtin_amdgcn_mfma_f32_16x16x32_bf16(xhB, BhX[ntl], aB1[ntl], 0, 0, 0);
            aB1[ntl] = __builtin_amdgcn_mfma_f32_16x16x32_bf16(xlB, BhX[ntl], aB1[ntl], 0, 0, 0);
            aB1[ntl] = __builtin_amdgcn_mfma_f32_16x16x32_bf16(xhB, BlX[ntl], aB1[ntl], 0, 0, 0);
        }

        // ---- layer-3 partials: relu * w3, DPP-reduce, both groups ----
        f32x4 rvA = (f32x4){0.f, 0.f, 0.f, 0.f};
        f32x4 rvB = (f32x4){0.f, 0.f, 0.f, 0.f};
        const f32x4 z4 = (f32x4){0.f, 0.f, 0.f, 0.f};
#pragma unroll
        for (int ntl = 0; ntl < 2; ++ntl) {
            const f32x4 wsp = (f32x4){w3v[ntl], w3v[ntl], w3v[ntl], w3v[ntl]};
            const f32x4 fsA = aA0[ntl] + aA1[ntl];
            rvA = __builtin_elementwise_fma(__builtin_elementwise_max(fsA, z4), wsp, rvA);
            const f32x4 fsB = aB0[ntl] + aB1[ntl];
            rvB = __builtin_elementwise_fma(__builtin_elementwise_max(fsB, z4), wsp, rvB);
        }
        const float rA0 = red16(rvA[0]), rA1 = red16(rvA[1]);
        const float rA2 = red16(rvA[2]), rA3 = red16(rvA[3]);
        const float rB0 = red16(rvB[0]), rB1 = red16(rvB[1]);
        const float rB2 = red16(rvB[2]), rB3 = red16(rvB[3]);

        // lanes r4<4 of each g own sample 4g+r4; publish both groups' partials
        const int r4 = l & 15;
        float wvA = rA0;
        wvA = (r4 == 1) ? rA1 : wvA;
        wvA = (r4 == 2) ? rA2 : wvA;
        wvA = (r4 == 3) ? rA3 : wvA;
        float wvB = rB0;
        wvB = (r4 == 1) ? rB1 : wvB;
        wvB = (r4 == 2) ? rB2 : wvB;
        wvB = (r4 == 3) ? rB3 : wvB;
        if (q == 0) { wvA += b3s; wvB += b3s; }   // bias counted once per MLP
        if (r4 < 4) {
            ((float*)&ex[4 * g + r4])[wid]      = wvA;
            ((float*)&ex[16 + 4 * g + r4])[wid] = wvB;
        }
        __syncthreads();                       // barrier B

        // ---- merge partials, SDE update, both groups ----
        const float4 pvA = ex[s];
        const float4 pvB = ex[16 + s];
        const float piA = pvA.x + pvA.z;
        const float cA  = __expf(pvA.y + pvA.w);
        const float piB = pvB.x + pvB.z;
        const float cB  = __expf(pvB.y + pvB.w);
        const float drA = MU_DT + fmaf(NU, vbmA, SIGMA * vdcA);
        const float drB = MU_DT + fmaf(NU, vbmB, SIGMA * vdcB);
        float xnA = xA + piA * xA * drA - cA * xA * DT;
        xnA = fmaxf(xnA - FLOORV, 0.0f) + FLOORV;
        xA = xnA;
        float xnB = xB + piB * xB * drB - cB * xB * DT;
        xnB = fmaxf(xnB - FLOORV, 0.0f) + FLOORV;
        xB = xnB;

        if (tid < 16)      traj[i + 1][tid] = xA;
        else if (tid < 32) traj[i + 1][tid] = xB;
    }
    __syncthreads();

    // ---- epilogue: coalesced output write {t, x} for 32 samples ----
    const int TOT = 32 * (N + 1) * 2;            // 6464
#pragma unroll
    for (int k = 0; k < 26; ++k) {
        const int e = tid + 256 * k;
        if (e < TOT) {
            const int sample = e / (2 * (N + 1));
            const int r      = e - sample * (2 * (N + 1));
            const int i      = r >> 1;
            const float v    = (r & 1) ? traj[i][sample] : (float)i * DT;
            out[(size_t)b0 * (2 * (N + 1)) + e] = v;
        }
    }
}

extern "C" void kernel_launch(void* const* d_in, const int* in_sizes, int n_in,
                              void* d_out, int out_size, void* d_ws, size_t ws_size,
                              hipStream_t stream) {
    const float* bm        = (const float*)d_in[0];
    const float* cn        = (const float*)d_in[1];
    const float* typeVec   = (const float*)d_in[2];
    const float* mx        = (const float*)d_in[3];
    const float* mc        = (const float*)d_in[4];
    const float* initial   = (const float*)d_in[5];
    const float* bn_gamma  = (const float*)d_in[6];
    const float* bn_beta   = (const float*)d_in[7];
    const float* bnc_gamma = (const float*)d_in[8];
    const float* bnc_beta  = (const float*)d_in[9];
    const float* w1  = (const float*)d_in[10];
    const float* b1  = (const float*)d_in[11];
    const float* w2  = (const float*)d_in[12];
    const float* b2  = (const float*)d_in[13];
    const float* w3  = (const float*)d_in[14];
    const float* b3  = (const float*)d_in[15];
    const float* wc1 = (const float*)d_in[16];
    const float* bc1 = (const float*)d_in[17];
    const float* wc2 = (const float*)d_in[18];
    const float* bc2 = (const float*)d_in[19];
    const float* wc3 = (const float*)d_in[20];
    const float* bc3 = (const float*)d_in[21];
    float* wsp = (float*)d_ws;
    float* out = (float*)d_out;

    bn_stats_kernel<<<1, 1024, 0, stream>>>(typeVec, bn_gamma, bn_beta,
                                            bnc_gamma, bnc_beta, wsp);
    sim_kernel<<<256, 256, 0, stream>>>(bm, cn, typeVec, mx, mc, initial,
                                        w1, b1, w2, b2, w3, b3,
                                        wc1, bc1, wc2, bc2, wc3, bc3,
                                        wsp, out);
}

// Round 12
// 75.028 us; speedup vs baseline: 1.9423x; 1.8455x over previous
//
#include <hip/hip_runtime.h>
#include <math.h>

#define IN_DIM 5
constexpr int B = 8192;
constexpr int N = 100;
constexpr float DT     = 0.01f;
constexpr float MU_DT  = 0.001f;
constexpr float NU     = 0.2f;
constexpr float SIGMA  = 0.3f;
constexpr float BN_EPS = 1e-5f;
constexpr float FLOORV = 1e-4f;

typedef __attribute__((ext_vector_type(8))) short short8;
typedef __attribute__((ext_vector_type(4))) float f32x4;

// truncation-based bf16 split: h = hi + lo with |err| ~ 2^-16 |h| (weights)
__device__ __forceinline__ void bf16_split(float h, short& hi, short& lo) {
    unsigned int ub = __builtin_bit_cast(unsigned int, h);
    hi = (short)(ub >> 16);
    float hif = __builtin_bit_cast(float, ub & 0xffff0000u);
    float l = h - hif;
    lo = (short)(__builtin_bit_cast(unsigned int, l) >> 16);
}

// sum over each aligned 16-lane group via DPP (VALU only, no DS pipe)
__device__ __forceinline__ float red16(float v) {
#if __has_builtin(__builtin_amdgcn_update_dpp)
    int x;
    x = __builtin_amdgcn_update_dpp(0, __builtin_bit_cast(int, v), 0xB1, 0xF, 0xF, false);
    v += __builtin_bit_cast(float, x);
    x = __builtin_amdgcn_update_dpp(0, __builtin_bit_cast(int, v), 0x4E, 0xF, 0xF, false);
    v += __builtin_bit_cast(float, x);
    x = __builtin_amdgcn_update_dpp(0, __builtin_bit_cast(int, v), 0x141, 0xF, 0xF, false);
    v += __builtin_bit_cast(float, x);
    x = __builtin_amdgcn_update_dpp(0, __builtin_bit_cast(int, v), 0x140, 0xF, 0xF, false);
    v += __builtin_bit_cast(float, x);
    return v;
#else
    v += __shfl_xor(v, 1);
    v += __shfl_xor(v, 2);
    v += __shfl_xor(v, 4);
    v += __shfl_xor(v, 8);
    return v;
#endif
}

// ---------------------------------------------------------------------------
// Kernel 1: batch-norm stats (unchanged).
// ws[0..4]=alpha, ws[5..9]=beta', ws[10..14]=alphac, ws[15..19]=betac'
// ---------------------------------------------------------------------------
__global__ __launch_bounds__(1024) void bn_stats_kernel(
    const float* __restrict__ tv,
    const float* __restrict__ g1, const float* __restrict__ be1,
    const float* __restrict__ g2, const float* __restrict__ be2,
    float* __restrict__ ws)
{
    const int t = threadIdx.x;
    float s[IN_DIM] = {0.f, 0.f, 0.f, 0.f, 0.f};
    float q[IN_DIM] = {0.f, 0.f, 0.f, 0.f, 0.f};
    for (int r = t; r < B; r += 1024) {
        const float* row = tv + r * IN_DIM;
#pragma unroll
        for (int k = 0; k < IN_DIM; ++k) {
            const float v = row[k];
            s[k] += v;
            q[k] += v * v;
        }
    }
#pragma unroll
    for (int k = 0; k < IN_DIM; ++k) {
#pragma unroll
        for (int off = 32; off >= 1; off >>= 1) {
            s[k] += __shfl_xor(s[k], off);
            q[k] += __shfl_xor(q[k], off);
        }
    }
    __shared__ float red[16][2 * IN_DIM];
    const int w = t >> 6, lane = t & 63;
    if (lane == 0) {
#pragma unroll
        for (int k = 0; k < IN_DIM; ++k) {
            red[w][k] = s[k];
            red[w][IN_DIM + k] = q[k];
        }
    }
    __syncthreads();
    if (t == 0) {
#pragma unroll
        for (int k = 0; k < IN_DIM; ++k) {
            float S = 0.f, Q = 0.f;
            for (int u = 0; u < 16; ++u) { S += red[u][k]; Q += red[u][IN_DIM + k]; }
            const float mean = S / (float)B;
            const float var  = Q / (float)B - mean * mean;
            const float inv  = 1.0f / sqrtf(var + BN_EPS);
            const float a1 = inv * g1[k];
            const float a2 = inv * g2[k];
            ws[k]          = a1;
            ws[IN_DIM + k] = be1[k] - mean * a1;
            ws[10 + k]     = a2;
            ws[15 + k]     = be2[k] - mean * a2;
        }
    }
}

// ---------------------------------------------------------------------------
// Kernel 2: simulation. EXACT R5 structure (champion, 84.5us) minus the
// fl*wh product term. Block = 256 thr = 4 waves over the SAME 16 samples,
// wave w = (mlp = w&1, q = w>>1):
//   layer-1: only k-units u = 32q+8g+j (j<8); activation truncated to bf16
//   HI only (2-term product fh*wh + fh*wl = fh*w; dropped fl*w ~ 2^-9 rel,
//   est. +3e-3 absmax vs 2.7e-2 threshold). A-frags exchanged via FX LDS
//   (barrier A, traffic HALVED vs R5); layer-2/3: nt in {2q,2q+1}, 8 MFMAs
//   as two 2-deep chains per ntl; partials merged via ex (barrier B).
// All per-step inputs pre-staged in LDS; trajectory in LDS, coalesced
// epilogue write. Zero global ops inside the loop. Fast __expf.
// ---------------------------------------------------------------------------
__global__ __launch_bounds__(256, 2) void sim_kernel(
    const float* __restrict__ bm, const float* __restrict__ cn,
    const float* __restrict__ typeVec,
    const float* __restrict__ mx, const float* __restrict__ mc,
    const float* __restrict__ initial,
    const float* __restrict__ w1, const float* __restrict__ b1,
    const float* __restrict__ w2, const float* __restrict__ b2,
    const float* __restrict__ w3, const float* __restrict__ b3,
    const float* __restrict__ wc1, const float* __restrict__ bc1,
    const float* __restrict__ wc2, const float* __restrict__ bc2,
    const float* __restrict__ wc3, const float* __restrict__ bc3,
    const float* __restrict__ ws, float* __restrict__ out)
{
    const int tid = threadIdx.x;
    const int wid = tid >> 6;        // 0..3
    const int l   = tid & 63;
    const int s   = l & 15;          // sample (A-row) / unit-col index
    const int g   = l >> 4;          // k-octet / D-row group
    const int mlp = wid & 1;         // 0 = pi-MLP, 1 = c-MLP
    const int q   = wid >> 1;        // k-half (layer-1) and nt-half (layer-2/3)
    const int b0  = blockIdx.x * 16;

    __shared__ float4 SI[N][16];     // [step][sample] = {bm, dcn, mx, mc}
    __shared__ float  traj[N + 1][16];
    __shared__ float4 ex[16];        // [sample] = partials {w0,w1,w2,w3}
    __shared__ short8 FX[2][2][64];  // [mlp][q][lane] A-frag (hi only)

    // ---- stage per-step inputs, coalesced ----
#pragma unroll
    for (int k = 0; k < 8; ++k) {
        const int f  = tid + 256 * k;       // < 2048
        const int ss = f >> 7;
        const int ii = f & 127;
        if (ii < N) {
            const size_t r = (size_t)(b0 + ss);
            const float vb = bm[r * N + ii];
            const float c0 = cn[r * (N + 1) + ii];
            const float c1 = cn[r * (N + 1) + ii + 1];
            const float vx = mx[r * (N + 1) + ii];
            const float vc = mc[r * N + ii];
            SI[ii][ss] = make_float4(vb, c1 - c0, vx, vc);
        }
    }

    // ---- this wave's MLP parameter set ----
    const float* W1 = mlp ? wc1 : w1;
    const float* B1 = mlp ? bc1 : b1;
    const float* W2 = mlp ? wc2 : w2;
    const float* B2 = mlp ? bc2 : b2;
    const float* W3 = mlp ? wc3 : w3;
    const float* B3 = mlp ? bc3 : b3;
    const float* alpha = ws + (mlp ? 10 : 0);
    const float* beta  = ws + (mlp ? 15 : 5);

    // ---- B-fragments of W2 (hi/lo), per-role: O = kt=q, X = kt=1-q ----
    short8 BhO[2], BlO[2], BhX[2], BlX[2];
#pragma unroll
    for (int ntl = 0; ntl < 2; ++ntl) {
        const int nt = 2 * q + ntl;
        short8 fhO, flO, fhX, flX;
#pragma unroll
        for (int e = 0; e < 8; ++e) {
            short hi, lo;
            bf16_split(W2[(32 * q + 8 * g + e) * 64 + 16 * nt + s], hi, lo);
            fhO[e] = hi; flO[e] = lo;
            bf16_split(W2[(32 * (1 - q) + 8 * g + e) * 64 + 16 * nt + s], hi, lo);
            fhX[e] = hi; flX[e] = lo;
        }
        BhO[ntl] = fhO; BlO[ntl] = flO;
        BhX[ntl] = fhX; BlX[ntl] = flX;
    }

    // ---- bn affine for this lane's sample; layer-1 consts (8 units only) ----
    float bnv[IN_DIM];
    {
        const float* tvp = typeVec + (size_t)(b0 + s) * IN_DIM;
#pragma unroll
        for (int k = 0; k < IN_DIM; ++k)
            bnv[k] = fmaf(tvp[k], alpha[k], beta[k]);
    }
    float bs[8], wt[8], wx[8], wm[8], wcr[8];
#pragma unroll
    for (int j = 0; j < 8; ++j) {
        const int u = 32 * q + 8 * g + j;
        wt[j]  = W1[5 * 64 + u];
        wx[j]  = W1[6 * 64 + u];
        wm[j]  = W1[7 * 64 + u];
        wcr[j] = W1[8 * 64 + u];
        float a = B1[u];
#pragma unroll
        for (int k = 0; k < IN_DIM; ++k) a = fmaf(bnv[k], W1[k * 64 + u], a);
        bs[j] = a;
    }
    float b2v[2], w3v[2];
#pragma unroll
    for (int ntl = 0; ntl < 2; ++ntl) {
        const int nt = 2 * q + ntl;
        b2v[ntl] = B2[16 * nt + s];
        w3v[ntl] = W3[16 * nt + s];
    }
    const float b3s = B3[0];
    const float x0  = initial[0];

    float x = x0;
    if (tid < 16) traj[0][tid] = x0;
    __syncthreads();

    for (int i = 0; i < N; ++i) {
        const float t = (float)i * DT;
        const float4 in = SI[i][s];   // {bm, dcn, mx, mc}

        // ---- layer-1: 8 own k-units, relu, bf16-HI truncation only ----
        short8 oh;
#pragma unroll
        for (int j = 0; j < 8; ++j) {
            float h = bs[j];
            h = fmaf(t,    wt[j],  h);
            h = fmaf(x,    wx[j],  h);
            h = fmaf(in.z, wm[j],  h);
            h = fmaf(in.w, wcr[j], h);
            h = fmaxf(h, 0.0f);
            oh[j] = (short)(__builtin_bit_cast(unsigned int, h) >> 16);
        }
        // exchange A-frag (hi only) with partner wave (same mlp, other q)
        FX[mlp][q][l] = oh;
        __syncthreads();                       // barrier A
        const short8 xh = FX[mlp][1 - q][l];

        // ---- layer-2 MFMA: fh*(wh+wl) — two 2-deep chains per ntl ----
        f32x4 acc0[2], acc1[2];
#pragma unroll
        for (int ntl = 0; ntl < 2; ++ntl) {
            acc0[ntl] = (f32x4){b2v[ntl], b2v[ntl], b2v[ntl], b2v[ntl]};
            acc1[ntl] = (f32x4){0.f, 0.f, 0.f, 0.f};
        }
#pragma unroll
        for (int ntl = 0; ntl < 2; ++ntl) {
            acc0[ntl] = __builtin_amdgcn_mfma_f32_16x16x32_bf16(oh, BhO[ntl], acc0[ntl], 0, 0, 0);
            acc0[ntl] = __builtin_amdgcn_mfma_f32_16x16x32_bf16(oh, BlO[ntl], acc0[ntl], 0, 0, 0);
            acc1[ntl] = __builtin_amdgcn_mfma_f32_16x16x32_bf16(xh, BhX[ntl], acc1[ntl], 0, 0, 0);
            acc1[ntl] = __builtin_amdgcn_mfma_f32_16x16x32_bf16(xh, BlX[ntl], acc1[ntl], 0, 0, 0);
        }

        // ---- layer-3 partial: relu * w3, DPP-reduce over 16 unit-lanes ----
        float r0 = 0.f, r1 = 0.f, r2 = 0.f, r3 = 0.f;
#pragma unroll
        for (int ntl = 0; ntl < 2; ++ntl) {
            const f32x4 fs = acc0[ntl] + acc1[ntl];
            r0 = fmaf(fmaxf(fs[0], 0.f), w3v[ntl], r0);
            r1 = fmaf(fmaxf(fs[1], 0.f), w3v[ntl], r1);
            r2 = fmaf(fmaxf(fs[2], 0.f), w3v[ntl], r2);
            r3 = fmaf(fmaxf(fs[3], 0.f), w3v[ntl], r3);
        }
        r0 = red16(r0); r1 = red16(r1); r2 = red16(r2); r3 = red16(r3);

        // lanes r4<4 of each g own sample 4g+r4; publish this wave's partial
        const int r4 = l & 15;
        float wv = r0;
        wv = (r4 == 1) ? r1 : wv;
        wv = (r4 == 2) ? r2 : wv;
        wv = (r4 == 3) ? r3 : wv;
        if (q == 0) wv += b3s;    // bias counted once per MLP
        if (r4 < 4) ((float*)&ex[4 * g + r4])[wid] = wv;
        __syncthreads();                       // barrier B

        // ---- merge partials, SDE update (redundant in all 4 waves) ----
        const float4 pv = ex[s];   // {pi_q0, cl_q0, pi_q1, cl_q1}
        const float pi_v = pv.x + pv.z;
        const float c_v  = __expf(pv.y + pv.w);
        const float drift = MU_DT + fmaf(NU, in.x, SIGMA * in.y);
        float xn = x + pi_v * x * drift - c_v * x * DT;
        xn = fmaxf(xn - FLOORV, 0.0f) + FLOORV;
        x = xn;

        if (tid < 16) traj[i + 1][tid] = x;
    }
    __syncthreads();

    // ---- epilogue: coalesced output write {t, x} ----
    const int TOT = 16 * (N + 1) * 2;            // 3232
#pragma unroll
    for (int k = 0; k < 13; ++k) {
        const int e = tid + 256 * k;
        if (e < TOT) {
            const int sample = e / (2 * (N + 1));
            const int r      = e - sample * (2 * (N + 1));
            const int i      = r >> 1;
            const float v    = (r & 1) ? traj[i][sample] : (float)i * DT;
            out[(size_t)b0 * (2 * (N + 1)) + e] = v;
        }
    }
}

extern "C" void kernel_launch(void* const* d_in, const int* in_sizes, int n_in,
                              void* d_out, int out_size, void* d_ws, size_t ws_size,
                              hipStream_t stream) {
    const float* bm        = (const float*)d_in[0];
    const float* cn        = (const float*)d_in[1];
    const float* typeVec   = (const float*)d_in[2];
    const float* mx        = (const float*)d_in[3];
    const float* mc        = (const float*)d_in[4];
    const float* initial   = (const float*)d_in[5];
    const float* bn_gamma  = (const float*)d_in[6];
    const float* bn_beta   = (const float*)d_in[7];
    const float* bnc_gamma = (const float*)d_in[8];
    const float* bnc_beta  = (const float*)d_in[9];
    const float* w1  = (const float*)d_in[10];
    const float* b1  = (const float*)d_in[11];
    const float* w2  = (const float*)d_in[12];
    const float* b2  = (const float*)d_in[13];
    const float* w3  = (const float*)d_in[14];
    const float* b3  = (const float*)d_in[15];
    const float* wc1 = (const float*)d_in[16];
    const float* bc1 = (const float*)d_in[17];
    const float* wc2 = (const float*)d_in[18];
    const float* bc2 = (const float*)d_in[19];
    const float* wc3 = (const float*)d_in[20];
    const float* bc3 = (const float*)d_in[21];
    float* wsp = (float*)d_ws;
    float* out = (float*)d_out;

    bn_stats_kernel<<<1, 1024, 0, stream>>>(typeVec, bn_gamma, bn_beta,
                                            bnc_gamma, bnc_beta, wsp);
    sim_kernel<<<512, 256, 0, stream>>>(bm, cn, typeVec, mx, mc, initial,
                                        w1, b1, w2, b2, w3, b3,
                                        wc1, bc1, wc2, bc2, wc3, bc3,
                                        wsp, out);
}

// Round 13
// 71.707 us; speedup vs baseline: 2.0322x; 1.0463x over previous
//
#include <hip/hip_runtime.h>
#include <math.h>

#define IN_DIM 5
constexpr int B = 8192;
constexpr int N = 100;
constexpr float DT     = 0.01f;
constexpr float MU_DT  = 0.001f;
constexpr float NU     = 0.2f;
constexpr float SIGMA  = 0.3f;
constexpr float BN_EPS = 1e-5f;
constexpr float FLOORV = 1e-4f;

typedef __attribute__((ext_vector_type(8))) short short8;
typedef __attribute__((ext_vector_type(4))) float f32x4;

// round-to-nearest-even bf16 (for static weights, prologue only)
__device__ __forceinline__ short bf16_rtn(float w) {
    unsigned int u = __builtin_bit_cast(unsigned int, w);
    const unsigned int lsb = (u >> 16) & 1u;
    u += 0x7FFFu + lsb;
    return (short)(u >> 16);
}

// sum over each aligned 16-lane group via DPP (VALU only, no DS pipe)
__device__ __forceinline__ float red16(float v) {
#if __has_builtin(__builtin_amdgcn_update_dpp)
    int x;
    x = __builtin_amdgcn_update_dpp(0, __builtin_bit_cast(int, v), 0xB1, 0xF, 0xF, false);
    v += __builtin_bit_cast(float, x);
    x = __builtin_amdgcn_update_dpp(0, __builtin_bit_cast(int, v), 0x4E, 0xF, 0xF, false);
    v += __builtin_bit_cast(float, x);
    x = __builtin_amdgcn_update_dpp(0, __builtin_bit_cast(int, v), 0x141, 0xF, 0xF, false);
    v += __builtin_bit_cast(float, x);
    x = __builtin_amdgcn_update_dpp(0, __builtin_bit_cast(int, v), 0x140, 0xF, 0xF, false);
    v += __builtin_bit_cast(float, x);
    return v;
#else
    v += __shfl_xor(v, 1);
    v += __shfl_xor(v, 2);
    v += __shfl_xor(v, 4);
    v += __shfl_xor(v, 8);
    return v;
#endif
}

// ---------------------------------------------------------------------------
// Kernel 1: batch-norm stats (unchanged).
// ws[0..4]=alpha, ws[5..9]=beta', ws[10..14]=alphac, ws[15..19]=betac'
// ---------------------------------------------------------------------------
__global__ __launch_bounds__(1024) void bn_stats_kernel(
    const float* __restrict__ tv,
    const float* __restrict__ g1, const float* __restrict__ be1,
    const float* __restrict__ g2, const float* __restrict__ be2,
    float* __restrict__ ws)
{
    const int t = threadIdx.x;
    float s[IN_DIM] = {0.f, 0.f, 0.f, 0.f, 0.f};
    float q[IN_DIM] = {0.f, 0.f, 0.f, 0.f, 0.f};
    for (int r = t; r < B; r += 1024) {
        const float* row = tv + r * IN_DIM;
#pragma unroll
        for (int k = 0; k < IN_DIM; ++k) {
            const float v = row[k];
            s[k] += v;
            q[k] += v * v;
        }
    }
#pragma unroll
    for (int k = 0; k < IN_DIM; ++k) {
#pragma unroll
        for (int off = 32; off >= 1; off >>= 1) {
            s[k] += __shfl_xor(s[k], off);
            q[k] += __shfl_xor(q[k], off);
        }
    }
    __shared__ float red[16][2 * IN_DIM];
    const int w = t >> 6, lane = t & 63;
    if (lane == 0) {
#pragma unroll
        for (int k = 0; k < IN_DIM; ++k) {
            red[w][k] = s[k];
            red[w][IN_DIM + k] = q[k];
        }
    }
    __syncthreads();
    if (t == 0) {
#pragma unroll
        for (int k = 0; k < IN_DIM; ++k) {
            float S = 0.f, Q = 0.f;
            for (int u = 0; u < 16; ++u) { S += red[u][k]; Q += red[u][IN_DIM + k]; }
            const float mean = S / (float)B;
            const float var  = Q / (float)B - mean * mean;
            const float inv  = 1.0f / sqrtf(var + BN_EPS);
            const float a1 = inv * g1[k];
            const float a2 = inv * g2[k];
            ws[k]          = a1;
            ws[IN_DIM + k] = be1[k] - mean * a1;
            ws[10 + k]     = a2;
            ws[15 + k]     = be2[k] - mean * a2;
        }
    }
}

// ---------------------------------------------------------------------------
// Kernel 2: simulation. EXACT R12 structure (75.0us champion) with the
// weight-lo MFMA term also dropped: layer-2 product is now bf16(h) x bf16(W)
// with W rounded-to-nearest (prologue, free) -- 4 MFMAs/wave, 1-deep chains.
// Error: dropped fh*wl ~ 2^-9 rel, same order as the activation-lo cut that
// measurably cost nothing (R12 absmax unchanged at 7.8e-3); RTN weights
// halve the weight error to 2^-10 rel. Threshold margin 3.5x.
// Block = 256 thr = 4 waves over the SAME 16 samples, w = (mlp, q):
//   L1: k-units u=32q+8g+j (j<8), bf16-HI trunc, FX exchange (barrier A);
//   L2: nt in {2q,2q+1}, 4 MFMAs (own-frag x BO, exchanged-frag x BX);
//   L3: relu*w3, DPP-reduce, partials via ex (barrier B); SDE redundant.
// Inputs pre-staged in LDS; traj in LDS + coalesced epilogue; zero global
// ops in the loop.
// ---------------------------------------------------------------------------
__global__ __launch_bounds__(256, 2) void sim_kernel(
    const float* __restrict__ bm, const float* __restrict__ cn,
    const float* __restrict__ typeVec,
    const float* __restrict__ mx, const float* __restrict__ mc,
    const float* __restrict__ initial,
    const float* __restrict__ w1, const float* __restrict__ b1,
    const float* __restrict__ w2, const float* __restrict__ b2,
    const float* __restrict__ w3, const float* __restrict__ b3,
    const float* __restrict__ wc1, const float* __restrict__ bc1,
    const float* __restrict__ wc2, const float* __restrict__ bc2,
    const float* __restrict__ wc3, const float* __restrict__ bc3,
    const float* __restrict__ ws, float* __restrict__ out)
{
    const int tid = threadIdx.x;
    const int wid = tid >> 6;        // 0..3
    const int l   = tid & 63;
    const int s   = l & 15;          // sample (A-row) / unit-col index
    const int g   = l >> 4;          // k-octet / D-row group
    const int mlp = wid & 1;         // 0 = pi-MLP, 1 = c-MLP
    const int q   = wid >> 1;        // k-half (layer-1) and nt-half (layer-2/3)
    const int b0  = blockIdx.x * 16;

    __shared__ float4 SI[N][16];     // [step][sample] = {bm, dcn, mx, mc}
    __shared__ float  traj[N + 1][16];
    __shared__ float4 ex[16];        // [sample] = partials {w0,w1,w2,w3}
    __shared__ short8 FX[2][2][64];  // [mlp][q][lane] A-frag (hi only)

    // ---- stage per-step inputs, coalesced ----
#pragma unroll
    for (int k = 0; k < 8; ++k) {
        const int f  = tid + 256 * k;       // < 2048
        const int ss = f >> 7;
        const int ii = f & 127;
        if (ii < N) {
            const size_t r = (size_t)(b0 + ss);
            const float vb = bm[r * N + ii];
            const float c0 = cn[r * (N + 1) + ii];
            const float c1 = cn[r * (N + 1) + ii + 1];
            const float vx = mx[r * (N + 1) + ii];
            const float vc = mc[r * N + ii];
            SI[ii][ss] = make_float4(vb, c1 - c0, vx, vc);
        }
    }

    // ---- this wave's MLP parameter set ----
    const float* W1 = mlp ? wc1 : w1;
    const float* B1 = mlp ? bc1 : b1;
    const float* W2 = mlp ? wc2 : w2;
    const float* B2 = mlp ? bc2 : b2;
    const float* W3 = mlp ? wc3 : w3;
    const float* B3 = mlp ? bc3 : b3;
    const float* alpha = ws + (mlp ? 10 : 0);
    const float* beta  = ws + (mlp ? 15 : 5);

    // ---- B-fragments of W2 (RTN bf16), per-role: O = kt=q, X = kt=1-q ----
    short8 BO[2], BX[2];
#pragma unroll
    for (int ntl = 0; ntl < 2; ++ntl) {
        const int nt = 2 * q + ntl;
        short8 fO, fX;
#pragma unroll
        for (int e = 0; e < 8; ++e) {
            fO[e] = bf16_rtn(W2[(32 * q + 8 * g + e) * 64 + 16 * nt + s]);
            fX[e] = bf16_rtn(W2[(32 * (1 - q) + 8 * g + e) * 64 + 16 * nt + s]);
        }
        BO[ntl] = fO;
        BX[ntl] = fX;
    }

    // ---- bn affine for this lane's sample; layer-1 consts (8 units only) ----
    float bnv[IN_DIM];
    {
        const float* tvp = typeVec + (size_t)(b0 + s) * IN_DIM;
#pragma unroll
        for (int k = 0; k < IN_DIM; ++k)
            bnv[k] = fmaf(tvp[k], alpha[k], beta[k]);
    }
    float bs[8], wt[8], wx[8], wm[8], wcr[8];
#pragma unroll
    for (int j = 0; j < 8; ++j) {
        const int u = 32 * q + 8 * g + j;
        wt[j]  = W1[5 * 64 + u];
        wx[j]  = W1[6 * 64 + u];
        wm[j]  = W1[7 * 64 + u];
        wcr[j] = W1[8 * 64 + u];
        float a = B1[u];
#pragma unroll
        for (int k = 0; k < IN_DIM; ++k) a = fmaf(bnv[k], W1[k * 64 + u], a);
        bs[j] = a;
    }
    float b2v[2], w3v[2];
#pragma unroll
    for (int ntl = 0; ntl < 2; ++ntl) {
        const int nt = 2 * q + ntl;
        b2v[ntl] = B2[16 * nt + s];
        w3v[ntl] = W3[16 * nt + s];
    }
    const float b3s = B3[0];
    const float x0  = initial[0];

    float x = x0;
    if (tid < 16) traj[0][tid] = x0;
    __syncthreads();

    for (int i = 0; i < N; ++i) {
        const float t = (float)i * DT;
        const float4 in = SI[i][s];   // {bm, dcn, mx, mc}

        // ---- layer-1: 8 own k-units, relu, bf16-HI truncation ----
        short8 oh;
#pragma unroll
        for (int j = 0; j < 8; ++j) {
            float h = bs[j];
            h = fmaf(t,    wt[j],  h);
            h = fmaf(x,    wx[j],  h);
            h = fmaf(in.z, wm[j],  h);
            h = fmaf(in.w, wcr[j], h);
            h = fmaxf(h, 0.0f);
            oh[j] = (short)(__builtin_bit_cast(unsigned int, h) >> 16);
        }
        // exchange A-frag (hi only) with partner wave (same mlp, other q)
        FX[mlp][q][l] = oh;
        __syncthreads();                       // barrier A
        const short8 xh = FX[mlp][1 - q][l];

        // ---- layer-2 MFMA: 4 independent 1-deep chains ----
        f32x4 acc0[2], acc1[2];
#pragma unroll
        for (int ntl = 0; ntl < 2; ++ntl) {
            acc0[ntl] = (f32x4){b2v[ntl], b2v[ntl], b2v[ntl], b2v[ntl]};
            acc1[ntl] = (f32x4){0.f, 0.f, 0.f, 0.f};
        }
#pragma unroll
        for (int ntl = 0; ntl < 2; ++ntl) {
            acc0[ntl] = __builtin_amdgcn_mfma_f32_16x16x32_bf16(oh, BO[ntl], acc0[ntl], 0, 0, 0);
            acc1[ntl] = __builtin_amdgcn_mfma_f32_16x16x32_bf16(xh, BX[ntl], acc1[ntl], 0, 0, 0);
        }

        // ---- layer-3 partial: relu * w3, DPP-reduce over 16 unit-lanes ----
        float r0 = 0.f, r1 = 0.f, r2 = 0.f, r3 = 0.f;
#pragma unroll
        for (int ntl = 0; ntl < 2; ++ntl) {
            const f32x4 fs = acc0[ntl] + acc1[ntl];
            r0 = fmaf(fmaxf(fs[0], 0.f), w3v[ntl], r0);
            r1 = fmaf(fmaxf(fs[1], 0.f), w3v[ntl], r1);
            r2 = fmaf(fmaxf(fs[2], 0.f), w3v[ntl], r2);
            r3 = fmaf(fmaxf(fs[3], 0.f), w3v[ntl], r3);
        }
        r0 = red16(r0); r1 = red16(r1); r2 = red16(r2); r3 = red16(r3);

        // lanes r4<4 of each g own sample 4g+r4; publish this wave's partial
        const int r4 = l & 15;
        float wv = r0;
        wv = (r4 == 1) ? r1 : wv;
        wv = (r4 == 2) ? r2 : wv;
        wv = (r4 == 3) ? r3 : wv;
        if (q == 0) wv += b3s;    // bias counted once per MLP
        if (r4 < 4) ((float*)&ex[4 * g + r4])[wid] = wv;
        __syncthreads();                       // barrier B

        // ---- merge partials, SDE update (redundant in all 4 waves) ----
        const float4 pv = ex[s];   // {pi_q0, cl_q0, pi_q1, cl_q1}
        const float pi_v = pv.x + pv.z;
        const float c_v  = __expf(pv.y + pv.w);
        const float drift = MU_DT + fmaf(NU, in.x, SIGMA * in.y);
        float xn = x + pi_v * x * drift - c_v * x * DT;
        xn = fmaxf(xn - FLOORV, 0.0f) + FLOORV;
        x = xn;

        if (tid < 16) traj[i + 1][tid] = x;
    }
    __syncthreads();

    // ---- epilogue: coalesced output write {t, x} ----
    const int TOT = 16 * (N + 1) * 2;            // 3232
#pragma unroll
    for (int k = 0; k < 13; ++k) {
        const int e = tid + 256 * k;
        if (e < TOT) {
            const int sample = e / (2 * (N + 1));
            const int r      = e - sample * (2 * (N + 1));
            const int i      = r >> 1;
            const float v    = (r & 1) ? traj[i][sample] : (float)i * DT;
            out[(size_t)b0 * (2 * (N + 1)) + e] = v;
        }
    }
}

extern "C" void kernel_launch(void* const* d_in, const int* in_sizes, int n_in,
                              void* d_out, int out_size, void* d_ws, size_t ws_size,
                              hipStream_t stream) {
    const float* bm        = (const float*)d_in[0];
    const float* cn        = (const float*)d_in[1];
    const float* typeVec   = (const float*)d_in[2];
    const float* mx        = (const float*)d_in[3];
    const float* mc        = (const float*)d_in[4];
    const float* initial   = (const float*)d_in[5];
    const float* bn_gamma  = (const float*)d_in[6];
    const float* bn_beta   = (const float*)d_in[7];
    const float* bnc_gamma = (const float*)d_in[8];
    const float* bnc_beta  = (const float*)d_in[9];
    const float* w1  = (const float*)d_in[10];
    const float* b1  = (const float*)d_in[11];
    const float* w2  = (const float*)d_in[12];
    const float* b2  = (const float*)d_in[13];
    const float* w3  = (const float*)d_in[14];
    const float* b3  = (const float*)d_in[15];
    const float* wc1 = (const float*)d_in[16];
    const float* bc1 = (const float*)d_in[17];
    const float* wc2 = (const float*)d_in[18];
    const float* bc2 = (const float*)d_in[19];
    const float* wc3 = (const float*)d_in[20];
    const float* bc3 = (const float*)d_in[21];
    float* wsp = (float*)d_ws;
    float* out = (float*)d_out;

    bn_stats_kernel<<<1, 1024, 0, stream>>>(typeVec, bn_gamma, bn_beta,
                                            bnc_gamma, bnc_beta, wsp);
    sim_kernel<<<512, 256, 0, stream>>>(bm, cn, typeVec, mx, mc, initial,
                                        w1, b1, w2, b2, w3, b3,
                                        wc1, bc1, wc2, bc2, wc3, bc3,
                                        wsp, out);
}

// Round 16
// 71.560 us; speedup vs baseline: 2.0364x; 1.0021x over previous
//
#include <hip/hip_runtime.h>
#include <math.h>

#define IN_DIM 5
constexpr int B = 8192;
constexpr int N = 100;
constexpr float DT     = 0.01f;
constexpr float MU_DT  = 0.001f;
constexpr float NU     = 0.2f;
constexpr float SIGMA  = 0.3f;
constexpr float BN_EPS = 1e-5f;
constexpr float FLOORV = 1e-4f;

typedef __attribute__((ext_vector_type(8))) short short8;
typedef __attribute__((ext_vector_type(4))) float f32x4;

// round-to-nearest-even bf16 (for static weights, prologue only)
__device__ __forceinline__ short bf16_rtn(float w) {
    unsigned int u = __builtin_bit_cast(unsigned int, w);
    const unsigned int lsb = (u >> 16) & 1u;
    u += 0x7FFFu + lsb;
    return (short)(u >> 16);
}

// sum over each aligned 16-lane group via DPP (VALU only, no DS pipe)
__device__ __forceinline__ float red16(float v) {
#if __has_builtin(__builtin_amdgcn_update_dpp)
    int x;
    x = __builtin_amdgcn_update_dpp(0, __builtin_bit_cast(int, v), 0xB1, 0xF, 0xF, false);
    v += __builtin_bit_cast(float, x);
    x = __builtin_amdgcn_update_dpp(0, __builtin_bit_cast(int, v), 0x4E, 0xF, 0xF, false);
    v += __builtin_bit_cast(float, x);
    x = __builtin_amdgcn_update_dpp(0, __builtin_bit_cast(int, v), 0x141, 0xF, 0xF, false);
    v += __builtin_bit_cast(float, x);
    x = __builtin_amdgcn_update_dpp(0, __builtin_bit_cast(int, v), 0x140, 0xF, 0xF, false);
    v += __builtin_bit_cast(float, x);
    return v;
#else
    v += __shfl_xor(v, 1);
    v += __shfl_xor(v, 2);
    v += __shfl_xor(v, 4);
    v += __shfl_xor(v, 8);
    return v;
#endif
}

// ---------------------------------------------------------------------------
// Kernel 1: batch-norm stats.
// ws[0..4]=alpha, ws[5..9]=beta', ws[10..14]=alphac, ws[15..19]=betac'
// ---------------------------------------------------------------------------
__global__ __launch_bounds__(1024) void bn_stats_kernel(
    const float* __restrict__ tv,
    const float* __restrict__ g1, const float* __restrict__ be1,
    const float* __restrict__ g2, const float* __restrict__ be2,
    float* __restrict__ ws)
{
    const int t = threadIdx.x;
    float s[IN_DIM] = {0.f, 0.f, 0.f, 0.f, 0.f};
    float q[IN_DIM] = {0.f, 0.f, 0.f, 0.f, 0.f};
    for (int r = t; r < B; r += 1024) {
        const float* row = tv + r * IN_DIM;
#pragma unroll
        for (int k = 0; k < IN_DIM; ++k) {
            const float v = row[k];
            s[k] += v;
            q[k] += v * v;
        }
    }
#pragma unroll
    for (int k = 0; k < IN_DIM; ++k) {
#pragma unroll
        for (int off = 32; off >= 1; off >>= 1) {
            s[k] += __shfl_xor(s[k], off);
            q[k] += __shfl_xor(q[k], off);
        }
    }
    __shared__ float red[16][2 * IN_DIM];
    const int w = t >> 6, lane = t & 63;
    if (lane == 0) {
#pragma unroll
        for (int k = 0; k < IN_DIM; ++k) {
            red[w][k] = s[k];
            red[w][IN_DIM + k] = q[k];
        }
    }
    __syncthreads();
    if (t == 0) {
#pragma unroll
        for (int k = 0; k < IN_DIM; ++k) {
            float S = 0.f, Q = 0.f;
            for (int u = 0; u < 16; ++u) { S += red[u][k]; Q += red[u][IN_DIM + k]; }
            const float mean = S / (float)B;
            const float var  = Q / (float)B - mean * mean;
            const float inv  = 1.0f / sqrtf(var + BN_EPS);
            const float a1 = inv * g1[k];
            const float a2 = inv * g2[k];
            ws[k]          = a1;
            ws[IN_DIM + k] = be1[k] - mean * a1;
            ws[10 + k]     = a2;
            ws[15 + k]     = be2[k] - mean * a2;
        }
    }
}

// ---------------------------------------------------------------------------
// Kernel 2: simulation — R13 VERBATIM (71.7us, passed, absmax 7.8e-3).
// The converged champion. Block = 256 thr = 4 waves over the SAME 16
// samples, wave w = (mlp = w&1, q = w>>1):
//   L1: k-units u=32q+8g+j (j<8), scalar fmaf chain, bf16-HI truncation
//       of activations; A-frag exchanged via FX LDS (barrier A).
//   L2: nt in {2q,2q+1}, 4 MFMAs (RTN-bf16 weights), 1-deep chains.
//   L3: relu*w3, DPP-reduce (red16), partials merged via ex (barrier B);
//       SDE update redundant in all 4 waves (x stays in-register).
// Inputs pre-staged in LDS (SI); trajectory in LDS + coalesced epilogue;
// zero global ops inside the loop. Fast __expf.
// NOTE: pk-math L1 / SI prefetch micro-cuts REVERTED — every component is
// individually silicon-validated but their combination on this skeleton
// failed twice (R14/R15) with the trajectory-collapse signature
// (absmax = max_ref - FLOOR); suspected backend miscompile. Do not re-add.
// ---------------------------------------------------------------------------
__global__ __launch_bounds__(256, 2) void sim_kernel(
    const float* __restrict__ bm, const float* __restrict__ cn,
    const float* __restrict__ typeVec,
    const float* __restrict__ mx, const float* __restrict__ mc,
    const float* __restrict__ initial,
    const float* __restrict__ w1, const float* __restrict__ b1,
    const float* __restrict__ w2, const float* __restrict__ b2,
    const float* __restrict__ w3, const float* __restrict__ b3,
    const float* __restrict__ wc1, const float* __restrict__ bc1,
    const float* __restrict__ wc2, const float* __restrict__ bc2,
    const float* __restrict__ wc3, const float* __restrict__ bc3,
    const float* __restrict__ ws, float* __restrict__ out)
{
    const int tid = threadIdx.x;
    const int wid = tid >> 6;        // 0..3
    const int l   = tid & 63;
    const int s   = l & 15;          // sample (A-row) / unit-col index
    const int g   = l >> 4;          // k-octet / D-row group
    const int mlp = wid & 1;         // 0 = pi-MLP, 1 = c-MLP
    const int q   = wid >> 1;        // k-half (layer-1) and nt-half (layer-2/3)
    const int b0  = blockIdx.x * 16;

    __shared__ float4 SI[N][16];     // [step][sample] = {bm, dcn, mx, mc}
    __shared__ float  traj[N + 1][16];
    __shared__ float4 ex[16];        // [sample] = partials {w0,w1,w2,w3}
    __shared__ short8 FX[2][2][64];  // [mlp][q][lane] A-frag (hi only)

    // ---- stage per-step inputs, coalesced ----
#pragma unroll
    for (int k = 0; k < 8; ++k) {
        const int f  = tid + 256 * k;       // < 2048
        const int ss = f >> 7;
        const int ii = f & 127;
        if (ii < N) {
            const size_t r = (size_t)(b0 + ss);
            const float vb = bm[r * N + ii];
            const float c0 = cn[r * (N + 1) + ii];
            const float c1 = cn[r * (N + 1) + ii + 1];
            const float vx = mx[r * (N + 1) + ii];
            const float vc = mc[r * N + ii];
            SI[ii][ss] = make_float4(vb, c1 - c0, vx, vc);
        }
    }

    // ---- this wave's MLP parameter set ----
    const float* W1 = mlp ? wc1 : w1;
    const float* B1 = mlp ? bc1 : b1;
    const float* W2 = mlp ? wc2 : w2;
    const float* B2 = mlp ? bc2 : b2;
    const float* W3 = mlp ? wc3 : w3;
    const float* B3 = mlp ? bc3 : b3;
    const float* alpha = ws + (mlp ? 10 : 0);
    const float* beta  = ws + (mlp ? 15 : 5);

    // ---- B-fragments of W2 (RTN bf16), per-role: O = kt=q, X = kt=1-q ----
    short8 BO[2], BX[2];
#pragma unroll
    for (int ntl = 0; ntl < 2; ++ntl) {
        const int nt = 2 * q + ntl;
        short8 fO, fX;
#pragma unroll
        for (int e = 0; e < 8; ++e) {
            fO[e] = bf16_rtn(W2[(32 * q + 8 * g + e) * 64 + 16 * nt + s]);
            fX[e] = bf16_rtn(W2[(32 * (1 - q) + 8 * g + e) * 64 + 16 * nt + s]);
        }
        BO[ntl] = fO;
        BX[ntl] = fX;
    }

    // ---- bn affine for this lane's sample; layer-1 consts (8 units only) ----
    float bnv[IN_DIM];
    {
        const float* tvp = typeVec + (size_t)(b0 + s) * IN_DIM;
#pragma unroll
        for (int k = 0; k < IN_DIM; ++k)
            bnv[k] = fmaf(tvp[k], alpha[k], beta[k]);
    }
    float bs[8], wt[8], wx[8], wm[8], wcr[8];
#pragma unroll
    for (int j = 0; j < 8; ++j) {
        const int u = 32 * q + 8 * g + j;
        wt[j]  = W1[5 * 64 + u];
        wx[j]  = W1[6 * 64 + u];
        wm[j]  = W1[7 * 64 + u];
        wcr[j] = W1[8 * 64 + u];
        float a = B1[u];
#pragma unroll
        for (int k = 0; k < IN_DIM; ++k) a = fmaf(bnv[k], W1[k * 64 + u], a);
        bs[j] = a;
    }
    float b2v[2], w3v[2];
#pragma unroll
    for (int ntl = 0; ntl < 2; ++ntl) {
        const int nt = 2 * q + ntl;
        b2v[ntl] = B2[16 * nt + s];
        w3v[ntl] = W3[16 * nt + s];
    }
    const float b3s = B3[0];
    const float x0  = initial[0];

    float x = x0;
    if (tid < 16) traj[0][tid] = x0;
    __syncthreads();

    for (int i = 0; i < N; ++i) {
        const float t = (float)i * DT;
        const float4 in = SI[i][s];   // {bm, dcn, mx, mc}

        // ---- layer-1: 8 own k-units, relu, bf16-HI truncation ----
        short8 oh;
#pragma unroll
        for (int j = 0; j < 8; ++j) {
            float h = bs[j];
            h = fmaf(t,    wt[j],  h);
            h = fmaf(x,    wx[j],  h);
            h = fmaf(in.z, wm[j],  h);
            h = fmaf(in.w, wcr[j], h);
            h = fmaxf(h, 0.0f);
            oh[j] = (short)(__builtin_bit_cast(unsigned int, h) >> 16);
        }
        // exchange A-frag (hi only) with partner wave (same mlp, other q)
        FX[mlp][q][l] = oh;
        __syncthreads();                       // barrier A
        const short8 xh = FX[mlp][1 - q][l];

        // ---- layer-2 MFMA: 4 independent 1-deep chains ----
        f32x4 acc0[2], acc1[2];
#pragma unroll
        for (int ntl = 0; ntl < 2; ++ntl) {
            acc0[ntl] = (f32x4){b2v[ntl], b2v[ntl], b2v[ntl], b2v[ntl]};
            acc1[ntl] = (f32x4){0.f, 0.f, 0.f, 0.f};
        }
#pragma unroll
        for (int ntl = 0; ntl < 2; ++ntl) {
            acc0[ntl] = __builtin_amdgcn_mfma_f32_16x16x32_bf16(oh, BO[ntl], acc0[ntl], 0, 0, 0);
            acc1[ntl] = __builtin_amdgcn_mfma_f32_16x16x32_bf16(xh, BX[ntl], acc1[ntl], 0, 0, 0);
        }

        // ---- layer-3 partial: relu * w3, DPP-reduce over 16 unit-lanes ----
        float r0 = 0.f, r1 = 0.f, r2 = 0.f, r3 = 0.f;
#pragma unroll
        for (int ntl = 0; ntl < 2; ++ntl) {
            const f32x4 fs = acc0[ntl] + acc1[ntl];
            r0 = fmaf(fmaxf(fs[0], 0.f), w3v[ntl], r0);
            r1 = fmaf(fmaxf(fs[1], 0.f), w3v[ntl], r1);
            r2 = fmaf(fmaxf(fs[2], 0.f), w3v[ntl], r2);
            r3 = fmaf(fmaxf(fs[3], 0.f), w3v[ntl], r3);
        }
        r0 = red16(r0); r1 = red16(r1); r2 = red16(r2); r3 = red16(r3);

        // lanes r4<4 of each g own sample 4g+r4; publish this wave's partial
        const int r4 = l & 15;
        float wv = r0;
        wv = (r4 == 1) ? r1 : wv;
        wv = (r4 == 2) ? r2 : wv;
        wv = (r4 == 3) ? r3 : wv;
        if (q == 0) wv += b3s;    // bias counted once per MLP
        if (r4 < 4) ((float*)&ex[4 * g + r4])[wid] = wv;
        __syncthreads();                       // barrier B

        // ---- merge partials, SDE update (redundant in all 4 waves) ----
        const float4 pv = ex[s];   // {pi_q0, cl_q0, pi_q1, cl_q1}
        const float pi_v = pv.x + pv.z;
        const float c_v  = __expf(pv.y + pv.w);
        const float drift = MU_DT + fmaf(NU, in.x, SIGMA * in.y);
        float xn = x + pi_v * x * drift - c_v * x * DT;
        xn = fmaxf(xn - FLOORV, 0.0f) + FLOORV;
        x = xn;

        if (tid < 16) traj[i + 1][tid] = x;
    }
    __syncthreads();

    // ---- epilogue: coalesced output write {t, x} ----
    const int TOT = 16 * (N + 1) * 2;            // 3232
#pragma unroll
    for (int k = 0; k < 13; ++k) {
        const int e = tid + 256 * k;
        if (e < TOT) {
            const int sample = e / (2 * (N + 1));
            const int r      = e - sample * (2 * (N + 1));
            const int i      = r >> 1;
            const float v    = (r & 1) ? traj[i][sample] : (float)i * DT;
            out[(size_t)b0 * (2 * (N + 1)) + e] = v;
        }
    }
}

extern "C" void kernel_launch(void* const* d_in, const int* in_sizes, int n_in,
                              void* d_out, int out_size, void* d_ws, size_t ws_size,
                              hipStream_t stream) {
    const float* bm        = (const float*)d_in[0];
    const float* cn        = (const float*)d_in[1];
    const float* typeVec   = (const float*)d_in[2];
    const float* mx        = (const float*)d_in[3];
    const float* mc        = (const float*)d_in[4];
    const float* initial   = (const float*)d_in[5];
    const float* bn_gamma  = (const float*)d_in[6];
    const float* bn_beta   = (const float*)d_in[7];
    const float* bnc_gamma = (const float*)d_in[8];
    const float* bnc_beta  = (const float*)d_in[9];
    const float* w1  = (const float*)d_in[10];
    const float* b1  = (const float*)d_in[11];
    const float* w2  = (const float*)d_in[12];
    const float* b2  = (const float*)d_in[13];
    const float* w3  = (const float*)d_in[14];
    const float* b3  = (const float*)d_in[15];
    const float* wc1 = (const float*)d_in[16];
    const float* bc1 = (const float*)d_in[17];
    const float* wc2 = (const float*)d_in[18];
    const float* bc2 = (const float*)d_in[19];
    const float* wc3 = (const float*)d_in[20];
    const float* bc3 = (const float*)d_in[21];
    float* wsp = (float*)d_ws;
    float* out = (float*)d_out;

    bn_stats_kernel<<<1, 1024, 0, stream>>>(typeVec, bn_gamma, bn_beta,
                                            bnc_gamma, bnc_beta, wsp);
    sim_kernel<<<512, 256, 0, stream>>>(bm, cn, typeVec, mx, mc, initial,
                                        w1, b1, w2, b2, w3, b3,
                                        wc1, bc1, wc2, bc2, wc3, bc3,
                                        wsp, out);
}